// Round 9
// baseline (224.931 us; speedup 1.0000x reference)
//
#include <hip/hip_runtime.h>
#include <hip/hip_bf16.h>

typedef __attribute__((ext_vector_type(8))) short bf16x8;   // 8 bf16 = 4 VGPRs
typedef __attribute__((ext_vector_type(4))) float f32x4;
typedef unsigned short u16t;

#define DEVINL static __device__ __forceinline__

DEVINL u16t f2bf(float f) {
  union { __hip_bfloat16 h; u16t u; } cv;
  cv.h = __float2bfloat16(f);
  return cv.u;
}

DEVINL void async16(void* lds, const void* g) {
  __builtin_amdgcn_global_load_lds((const __attribute__((address_space(1))) void*)g,
                                   (__attribute__((address_space(3))) void*)lds,
                                   16, 0, 0);
}

// ---------------------------------------------------------------------------
// fp32 -> bf16 conversion for x (4M elems) + Wq/Wk/Wv/Wo (1M each).
// Wq/Wk/Wv destinations are CONTIGUOUS -> later treated as one [3072][1024].
// ---------------------------------------------------------------------------
__global__ __launch_bounds__(256) void convert_bf16(
    const float* __restrict__ x,  const float* __restrict__ wq,
    const float* __restrict__ wk, const float* __restrict__ wv,
    const float* __restrict__ wo,
    u16t* __restrict__ xb, u16t* __restrict__ wqb, u16t* __restrict__ wkb,
    u16t* __restrict__ wvb, u16t* __restrict__ wob) {
  const int blk = blockIdx.x;
  const float* src; u16t* dst; size_t off;
  if (blk < 4096)      { src = x;  dst = xb;  off = (size_t)blk * 1024; }
  else if (blk < 5120) { src = wq; dst = wqb; off = (size_t)(blk - 4096) * 1024; }
  else if (blk < 6144) { src = wk; dst = wkb; off = (size_t)(blk - 5120) * 1024; }
  else if (blk < 7168) { src = wv; dst = wvb; off = (size_t)(blk - 6144) * 1024; }
  else                 { src = wo; dst = wob; off = (size_t)(blk - 7168) * 1024; }
  const size_t i = off + (size_t)threadIdx.x * 4;
  const float4 v = *(const float4*)&src[i];
  ushort4 r;
  r.x = f2bf(v.x); r.y = f2bf(v.y); r.z = f2bf(v.z); r.w = f2bf(v.w);
  *(ushort4*)&dst[i] = r;
}

// ---------------------------------------------------------------------------
// C[m,n] = sum_k A[m,k]*B[n,k].  A:[M,K], B:[N,K] row-major bf16.
// BK=64 as TWO m97-style BK=32 panels (As[2][128][32]) -> same DMA contiguity
// and same at-floor LDS banking as m97, half the barrier drains.
// MODE 0: C0 row-major [M,N] fp32 (final projection).
// MODE 1 (fused QKV, N=3072): weight id nz = n0>>10 (block-uniform):
//   nz==0 (Q): head-split bf16 Cq[((b*16+h)*2048+t)*64+d]
//   nz==1 (K): frag-tiled Ck: ((t>>4)*8+(d>>3))*128 + (t&15)*8 + (d&7)
//   nz==2 (V): frag-tiled Cv: ((d>>4)*256+(t>>3))*128 + (d&15)*8 + (t&7)
// ---------------------------------------------------------------------------
template <int MODE>
__global__ __launch_bounds__(256) void gemm_bt(
    const u16t* __restrict__ A, const u16t* __restrict__ B,
    void* __restrict__ C0, void* __restrict__ C1, void* __restrict__ C2,
    int M, int N, int K) {
  __shared__ u16t As[2][128 * 32];
  __shared__ u16t Bs[2][128 * 32];

  const int tid = threadIdx.x;
  const int lane = tid & 63;
  const int w = tid >> 6;
  const int wm = w >> 1, wn = w & 1;
  const int quad = lane >> 4, cl = lane & 15;
  const int m0 = blockIdx.y * 128;
  const int n0 = blockIdx.x * 128;

  const int srow = lane >> 2;        // row within 16-row staging chunk
  const int scol = (lane & 3) * 8;   // 8-elem (16B) column chunk

  f32x4 acc[4][4] = {};

  for (int k0 = 0; k0 < K; k0 += 64) {
    __syncthreads();
    #pragma unroll
    for (int p = 0; p < 2; ++p)
      #pragma unroll
      for (int ii = 0; ii < 2; ++ii) {
        const int c = w + ii * 4;    // chunk 0..7 (16 rows each)
        async16(&As[p][c * 512], &A[(size_t)(m0 + c * 16 + srow) * K + k0 + p * 32 + scol]);
        async16(&Bs[p][c * 512], &B[(size_t)(n0 + c * 16 + srow) * K + k0 + p * 32 + scol]);
      }
    __syncthreads();                 // compiler drains vmcnt before s_barrier
    #pragma unroll
    for (int p = 0; p < 2; ++p) {
      bf16x8 af[4], bfr[4];
      #pragma unroll
      for (int i = 0; i < 4; ++i)
        af[i] = *(const bf16x8*)&As[p][(wm * 64 + i * 16 + cl) * 32 + quad * 8];
      #pragma unroll
      for (int j = 0; j < 4; ++j)
        bfr[j] = *(const bf16x8*)&Bs[p][(wn * 64 + j * 16 + cl) * 32 + quad * 8];
      #pragma unroll
      for (int i = 0; i < 4; ++i)
        #pragma unroll
        for (int j = 0; j < 4; ++j)
          acc[i][j] = __builtin_amdgcn_mfma_f32_16x16x32_bf16(af[i], bfr[j], acc[i][j], 0, 0, 0);
    }
  }

  const int nz = n0 >> 10;           // MODE1: weight id (block-uniform)
  #pragma unroll
  for (int i = 0; i < 4; ++i)
    #pragma unroll
    for (int j = 0; j < 4; ++j) {
      const int mb = m0 + wm * 64 + i * 16 + quad * 4;   // 4 consecutive m (t)
      const int n  = n0 + wn * 64 + j * 16 + cl;
      if (MODE == 0) {
        #pragma unroll
        for (int r = 0; r < 4; ++r)
          ((float*)C0)[(size_t)(mb + r) * N + n] = acc[i][j][r];
      } else {
        const int nw = n & 1023, h = nw >> 6, d = nw & 63;
        const int b = mb >> 11, tb = mb & 2047;
        const size_t bh = (size_t)(b * 16 + h);
        if (nz == 2) {
          ushort4 v4;
          v4.x = f2bf(acc[i][j][0]); v4.y = f2bf(acc[i][j][1]);
          v4.z = f2bf(acc[i][j][2]); v4.w = f2bf(acc[i][j][3]);
          const size_t addr = (bh << 17) +
              (size_t)(((d >> 4) * 256 + (tb >> 3)) * 128 + (d & 15) * 8 + (tb & 7));
          *(ushort4*)&((u16t*)C2)[addr] = v4;
        } else if (nz == 1) {
          const size_t basea = (bh << 17) +
              (size_t)(((tb >> 4) * 8 + (d >> 3)) * 128 + (d & 7));
          #pragma unroll
          for (int r = 0; r < 4; ++r)
            ((u16t*)C1)[basea + ((tb & 15) + r) * 8] = f2bf(acc[i][j][r]);
        } else {
          #pragma unroll
          for (int r = 0; r < 4; ++r)
            ((u16t*)C0)[(bh * 2048 + tb + r) * 64 + d] = f2bf(acc[i][j][r]);
        }
      }
    }
}

// ---------------------------------------------------------------------------
// Flash attention, barrier-free main loop + split-K. Grid (32 q-tiles, 32 bh),
// block 512 = 8 waves: wave w = (q-subwave w&3) x (key-half w>>2).
// Each wave: 16 q-rows, 8 key-tiles (half the keys). No-max softmax partials
// are ADDITIVE (o = o_a+o_b, l = l_a+l_b) -> one LDS merge at the end, no
// rescale. Waves/CU: 16 -> 32 (occupancy was the round-8 cap).
// Q: [bh][2048][64] bf16.  Kt/Vt: fragment-tiled.  Y: [4096][1024] bf16.
// ---------------------------------------------------------------------------
__global__ __launch_bounds__(512) void flash_attn(
    const u16t* __restrict__ Q, const u16t* __restrict__ Kt,
    const u16t* __restrict__ Vt, u16t* __restrict__ Y) {
  __shared__ u16t Ps[8 * 16 * 136];   // per-wave P scratch (34816 B); merge aliases

  const int tid = threadIdx.x;
  const int lane = tid & 63;
  const int w = tid >> 6;             // 0..7
  const int wq = w & 3;               // q sub-wave
  const int kh = w >> 2;              // key half
  const int quad = lane >> 4, cl = lane & 15;
  const int bh = blockIdx.y;
  const int q0 = blockIdx.x * 64;
  const u16t* Kb = Kt + ((size_t)bh << 17);
  const u16t* Vb = Vt + ((size_t)bh << 17);

  // Q A-fragments tile-invariant in registers (A[m=lane&15][k=quad*8+j])
  bf16x8 aq[2];
  #pragma unroll
  for (int ks = 0; ks < 2; ++ks)
    aq[ks] = *(const bf16x8*)&Q[((size_t)bh * 2048 + q0 + wq * 16 + cl) * 64 + ks * 32 + quad * 8];

  f32x4 o[4] = {};                    // O acc (C-layout): row=quad*4+r, col=ds*16+cl
  float lsum[4] = {0.f, 0.f, 0.f, 0.f};

  u16t* Pw = &Ps[w * 16 * 136];

  for (int jt = kh * 8; jt < kh * 8 + 8; ++jt) {
    const int j0 = jt * 128;

    // S = Q K^T : B-frag (js,ks) = Kb[(((j0>>4)+js)*8 + ks*4)*128 + lane*8]
    f32x4 s[8] = {};
    #pragma unroll
    for (int ks = 0; ks < 2; ++ks) {
      bf16x8 kf[8];
      #pragma unroll
      for (int js = 0; js < 8; ++js)
        kf[js] = *(const bf16x8*)&Kb[(size_t)((((j0 >> 4) + js) * 8 + ks * 4) * 128) + lane * 8];
      #pragma unroll
      for (int js = 0; js < 8; ++js)
        s[js] = __builtin_amdgcn_mfma_f32_16x16x32_bf16(aq[ks], kf[js], s[js], 0, 0, 0);
    }

    // p = exp(s/8) = exp2(s * 0.125/ln2); per-thread row partial sums
    #pragma unroll
    for (int js = 0; js < 8; ++js)
      #pragma unroll
      for (int r = 0; r < 4; ++r) {
        const float p = __builtin_exp2f(s[js][r] * 0.1803368801111593f);
        lsum[r] += p;
        Pw[(quad * 4 + r) * 136 + js * 16 + cl] = f2bf(p);   // C-layout scatter
      }
    // same-wave LDS write->read ordered by lgkmcnt (no barrier)

    // O += P @ V : A=P[m=cl][k], B-frag (ds,ks) = Vb[(ds*256+(j0>>3)+ks*4)*128+lane*8]
    #pragma unroll
    for (int ks = 0; ks < 4; ++ks) {
      const bf16x8 ap = *(const bf16x8*)&Pw[cl * 136 + ks * 32 + quad * 8];
      bf16x8 vf[4];
      #pragma unroll
      for (int ds = 0; ds < 4; ++ds)
        vf[ds] = *(const bf16x8*)&Vb[(size_t)((ds * 256 + (j0 >> 3) + ks * 4) * 128) + lane * 8];
      #pragma unroll
      for (int ds = 0; ds < 4; ++ds)
        o[ds] = __builtin_amdgcn_mfma_f32_16x16x32_bf16(ap, vf[ds], o[ds], 0, 0, 0);
    }
  }

  // split-K merge: upper half (kh=1) publishes o+l; lower adds. Stride 21
  // floats keeps the 64-lane access 2-way-bank-aliased only (gcd(21,32)=1).
  __syncthreads();                    // all P reads done -> Ps reusable
  float* M = (float*)Ps;
  if (kh == 1) {
    float* slot = &M[((size_t)((w - 4) * 64 + lane)) * 21];
    #pragma unroll
    for (int ds = 0; ds < 4; ++ds)
      #pragma unroll
      for (int r = 0; r < 4; ++r) slot[ds * 4 + r] = o[ds][r];
    #pragma unroll
    for (int r = 0; r < 4; ++r) slot[16 + r] = lsum[r];
  }
  __syncthreads();
  if (kh == 0) {
    const float* slot = &M[((size_t)(w * 64 + lane)) * 21];
    #pragma unroll
    for (int ds = 0; ds < 4; ++ds)
      #pragma unroll
      for (int r = 0; r < 4; ++r) o[ds][r] += slot[ds * 4 + r];
    #pragma unroll
    for (int r = 0; r < 4; ++r) {
      lsum[r] += slot[16 + r];
      #pragma unroll
      for (int msk = 1; msk < 16; msk <<= 1) lsum[r] += __shfl_xor(lsum[r], msk, 64);
    }
    const int b = bh >> 4, h = bh & 15;
    #pragma unroll
    for (int ds = 0; ds < 4; ++ds)
      #pragma unroll
      for (int r = 0; r < 4; ++r) {
        const int t = q0 + wq * 16 + quad * 4 + r;
        const int d = ds * 16 + cl;
        Y[((size_t)b * 2048 + t) * 1024 + h * 64 + d] = f2bf(o[ds][r] / lsum[r]);
      }
  }
}

extern "C" void kernel_launch(void* const* d_in, const int* in_sizes, int n_in,
                              void* d_out, int out_size, void* d_ws, size_t ws_size,
                              hipStream_t stream) {
  (void)in_sizes; (void)n_in; (void)out_size; (void)ws_size;
  const float* x  = (const float*)d_in[0];
  const float* Wq = (const float*)d_in[1];
  const float* Wk = (const float*)d_in[2];
  const float* Wv = (const float*)d_in[3];
  const float* Wo = (const float*)d_in[4];

  char* ws = (char*)d_ws;
  const size_t MB = 1024 * 1024;
  u16t* xb  = (u16t*)(ws);               // [4096][1024] bf16 (8 MB) — aliased by Yw
  u16t* Wqb = (u16t*)(ws + 8 * MB);      // Wq/Wk/Wv contiguous -> [3072][1024]
  u16t* Wkb = (u16t*)(ws + 10 * MB);
  u16t* Wvb = (u16t*)(ws + 12 * MB);
  u16t* Wob = (u16t*)(ws + 14 * MB);
  u16t* Qw  = (u16t*)(ws + 16 * MB);     // [32][2048][64] bf16 head-split
  u16t* Ktw = (u16t*)(ws + 24 * MB);     // [32] fragment-tiled K'
  u16t* Vtw = (u16t*)(ws + 32 * MB);     // [32] fragment-tiled V'
  u16t* Yw  = xb;                        // safe alias: xb dead after QKV gemm

  convert_bf16<<<8192, 256, 0, stream>>>(x, Wq, Wk, Wv, Wo, xb, Wqb, Wkb, Wvb, Wob);
  // fused QKV: B = [3072][1024], output target selected by n0>>10
  gemm_bt<1><<<dim3(24, 32), 256, 0, stream>>>(
      xb, Wqb, Qw, Ktw, Vtw, 4096, 3072, 1024);
  flash_attn<<<dim3(32, 32), 512, 0, stream>>>(Qw, Ktw, Vtw, Yw);
  gemm_bt<0><<<dim3(8, 32), 256, 0, stream>>>(
      Yw, Wob, d_out, d_out, d_out, 4096, 1024, 1024);
}

// Round 10
// 215.408 us; speedup vs baseline: 1.0442x; 1.0442x over previous
//
#include <hip/hip_runtime.h>
#include <hip/hip_bf16.h>

typedef __attribute__((ext_vector_type(8))) short bf16x8;   // 8 bf16 = 4 VGPRs
typedef __attribute__((ext_vector_type(4))) float f32x4;
typedef unsigned short u16t;

#define DEVINL static __device__ __forceinline__

DEVINL u16t f2bf(float f) {
  union { __hip_bfloat16 h; u16t u; } cv;
  cv.h = __float2bfloat16(f);
  return cv.u;
}

// fast bf16 cvt for finite non-negative values (round-half-up, 2 VALU ops)
DEVINL u16t f2bf_fast(float f) {
  union { float f; unsigned u; } c;
  c.f = f;
  return (u16t)((c.u + 0x8000u) >> 16);
}

DEVINL void async16(void* lds, const void* g) {
  __builtin_amdgcn_global_load_lds((const __attribute__((address_space(1))) void*)g,
                                   (__attribute__((address_space(3))) void*)lds,
                                   16, 0, 0);
}

// ---------------------------------------------------------------------------
// fp32 -> bf16 conversion for x (4M elems) + Wq/Wk/Wv/Wo (1M each).
// Wq/Wk/Wv destinations are CONTIGUOUS -> later treated as one [3072][1024].
// ---------------------------------------------------------------------------
__global__ __launch_bounds__(256) void convert_bf16(
    const float* __restrict__ x,  const float* __restrict__ wq,
    const float* __restrict__ wk, const float* __restrict__ wv,
    const float* __restrict__ wo,
    u16t* __restrict__ xb, u16t* __restrict__ wqb, u16t* __restrict__ wkb,
    u16t* __restrict__ wvb, u16t* __restrict__ wob) {
  const int blk = blockIdx.x;
  const float* src; u16t* dst; size_t off;
  if (blk < 4096)      { src = x;  dst = xb;  off = (size_t)blk * 1024; }
  else if (blk < 5120) { src = wq; dst = wqb; off = (size_t)(blk - 4096) * 1024; }
  else if (blk < 6144) { src = wk; dst = wkb; off = (size_t)(blk - 5120) * 1024; }
  else if (blk < 7168) { src = wv; dst = wvb; off = (size_t)(blk - 6144) * 1024; }
  else                 { src = wo; dst = wob; off = (size_t)(blk - 7168) * 1024; }
  const size_t i = off + (size_t)threadIdx.x * 4;
  const float4 v = *(const float4*)&src[i];
  ushort4 r;
  r.x = f2bf(v.x); r.y = f2bf(v.y); r.z = f2bf(v.z); r.w = f2bf(v.w);
  *(ushort4*)&dst[i] = r;
}

// ---------------------------------------------------------------------------
// C[m,n] = sum_k A[m,k]*B[n,k].  A:[M,K], B:[N,K] row-major bf16.
// BK=64 as TWO m97-style BK=32 panels. MODE 0: C0 row-major [M,N] fp32.
// MODE 1 (fused QKV, N=3072), nz = n0>>10:
//   nz==0 (Q): head-split bf16, PRE-SCALED by 0.125/ln2 (softmax fold)
//   nz==1 (K): frag-tiled: ((t>>4)*8+(d>>3))*128 + (t&15)*8 + (d&7)
//   nz==2 (V): frag-tiled: ((d>>4)*256+(t>>3))*128 + (d&15)*8 + (t&7)
// ---------------------------------------------------------------------------
template <int MODE>
__global__ __launch_bounds__(256) void gemm_bt(
    const u16t* __restrict__ A, const u16t* __restrict__ B,
    void* __restrict__ C0, void* __restrict__ C1, void* __restrict__ C2,
    int M, int N, int K) {
  __shared__ u16t As[2][128 * 32];
  __shared__ u16t Bs[2][128 * 32];

  const int tid = threadIdx.x;
  const int lane = tid & 63;
  const int w = tid >> 6;
  const int wm = w >> 1, wn = w & 1;
  const int quad = lane >> 4, cl = lane & 15;
  const int m0 = blockIdx.y * 128;
  const int n0 = blockIdx.x * 128;

  const int srow = lane >> 2;        // row within 16-row staging chunk
  const int scol = (lane & 3) * 8;   // 8-elem (16B) column chunk

  f32x4 acc[4][4] = {};

  for (int k0 = 0; k0 < K; k0 += 64) {
    __syncthreads();
    #pragma unroll
    for (int p = 0; p < 2; ++p)
      #pragma unroll
      for (int ii = 0; ii < 2; ++ii) {
        const int c = w + ii * 4;    // chunk 0..7 (16 rows each)
        async16(&As[p][c * 512], &A[(size_t)(m0 + c * 16 + srow) * K + k0 + p * 32 + scol]);
        async16(&Bs[p][c * 512], &B[(size_t)(n0 + c * 16 + srow) * K + k0 + p * 32 + scol]);
      }
    __syncthreads();                 // compiler drains vmcnt before s_barrier
    #pragma unroll
    for (int p = 0; p < 2; ++p) {
      bf16x8 af[4], bfr[4];
      #pragma unroll
      for (int i = 0; i < 4; ++i)
        af[i] = *(const bf16x8*)&As[p][(wm * 64 + i * 16 + cl) * 32 + quad * 8];
      #pragma unroll
      for (int j = 0; j < 4; ++j)
        bfr[j] = *(const bf16x8*)&Bs[p][(wn * 64 + j * 16 + cl) * 32 + quad * 8];
      #pragma unroll
      for (int i = 0; i < 4; ++i)
        #pragma unroll
        for (int j = 0; j < 4; ++j)
          acc[i][j] = __builtin_amdgcn_mfma_f32_16x16x32_bf16(af[i], bfr[j], acc[i][j], 0, 0, 0);
    }
  }

  const int nz = n0 >> 10;           // MODE1: weight id (block-uniform)
  #pragma unroll
  for (int i = 0; i < 4; ++i)
    #pragma unroll
    for (int j = 0; j < 4; ++j) {
      const int mb = m0 + wm * 64 + i * 16 + quad * 4;   // 4 consecutive m (t)
      const int n  = n0 + wn * 64 + j * 16 + cl;
      if (MODE == 0) {
        #pragma unroll
        for (int r = 0; r < 4; ++r)
          ((float*)C0)[(size_t)(mb + r) * N + n] = acc[i][j][r];
      } else {
        const int nw = n & 1023, h = nw >> 6, d = nw & 63;
        const int b = mb >> 11, tb = mb & 2047;
        const size_t bh = (size_t)(b * 16 + h);
        if (nz == 2) {
          ushort4 v4;
          v4.x = f2bf(acc[i][j][0]); v4.y = f2bf(acc[i][j][1]);
          v4.z = f2bf(acc[i][j][2]); v4.w = f2bf(acc[i][j][3]);
          const size_t addr = (bh << 17) +
              (size_t)(((d >> 4) * 256 + (tb >> 3)) * 128 + (d & 15) * 8 + (tb & 7));
          *(ushort4*)&((u16t*)C2)[addr] = v4;
        } else if (nz == 1) {
          const size_t basea = (bh << 17) +
              (size_t)(((tb >> 4) * 8 + (d >> 3)) * 128 + (d & 7));
          #pragma unroll
          for (int r = 0; r < 4; ++r)
            ((u16t*)C1)[basea + ((tb & 15) + r) * 8] = f2bf(acc[i][j][r]);
        } else {
          // Q: pre-scale by 0.125/ln2 so flash softmax is p = exp2(s)
          #pragma unroll
          for (int r = 0; r < 4; ++r)
            ((u16t*)C0)[(bh * 2048 + tb + r) * 64 + d] =
                f2bf(acc[i][j][r] * 0.18033688011112043f);
        }
      }
    }
}

// ---------------------------------------------------------------------------
// Flash attention, barrier-free (round-8 structure). Grid (32 q-tiles, 32 bh),
// block 256 = 4 independent waves; wave owns 16 q-rows, all 16 key-tiles.
// Q: [bh][2048][64] bf16 PRE-SCALED.  Kt/Vt: fragment-tiled.
// Softmax: no online max (scores ~N(0,1) pre-scale; exp2 arg |.|<~1.1,
// fp32-safe); p = exp2(s) (scale folded into Q); fast round-half-up bf16 cvt.
// LDS: only the wave-private P C-layout->A-layout roundtrip (17 KB).
// ---------------------------------------------------------------------------
__global__ __launch_bounds__(256) void flash_attn(
    const u16t* __restrict__ Q, const u16t* __restrict__ Kt,
    const u16t* __restrict__ Vt, u16t* __restrict__ Y) {
  __shared__ u16t Ps[4 * 16 * 136];   // per-wave P scratch

  const int tid = threadIdx.x;
  const int lane = tid & 63;
  const int w = tid >> 6;
  const int quad = lane >> 4, cl = lane & 15;
  const int bh = blockIdx.y;
  const int q0 = blockIdx.x * 64;
  const u16t* Kb = Kt + ((size_t)bh << 17);
  const u16t* Vb = Vt + ((size_t)bh << 17);

  // Q A-fragments tile-invariant in registers (A[m=lane&15][k=quad*8+j])
  bf16x8 aq[2];
  #pragma unroll
  for (int ks = 0; ks < 2; ++ks)
    aq[ks] = *(const bf16x8*)&Q[((size_t)bh * 2048 + q0 + w * 16 + cl) * 64 + ks * 32 + quad * 8];

  f32x4 o[4] = {};                    // O acc (C-layout): row=quad*4+r, col=ds*16+cl
  float lsum[4] = {0.f, 0.f, 0.f, 0.f};

  u16t* Pw = &Ps[w * 16 * 136];

  for (int jt = 0; jt < 16; ++jt) {
    const int j0 = jt * 128;

    // S = Qs K^T : B-frag (js,ks) = Kb[(((j0>>4)+js)*8 + ks*4)*128 + lane*8]
    f32x4 s[8] = {};
    #pragma unroll
    for (int ks = 0; ks < 2; ++ks) {
      bf16x8 kf[8];
      #pragma unroll
      for (int js = 0; js < 8; ++js)
        kf[js] = *(const bf16x8*)&Kb[(size_t)((((j0 >> 4) + js) * 8 + ks * 4) * 128) + lane * 8];
      #pragma unroll
      for (int js = 0; js < 8; ++js)
        s[js] = __builtin_amdgcn_mfma_f32_16x16x32_bf16(aq[ks], kf[js], s[js], 0, 0, 0);
    }

    // p = exp2(s) (scale pre-folded into Q); per-thread row partial sums
    #pragma unroll
    for (int js = 0; js < 8; ++js)
      #pragma unroll
      for (int r = 0; r < 4; ++r) {
        const float p = __builtin_exp2f(s[js][r]);
        lsum[r] += p;
        Pw[(quad * 4 + r) * 136 + js * 16 + cl] = f2bf_fast(p);  // C-layout scatter
      }
    // same-wave LDS write->read ordered by lgkmcnt (no barrier)

    // O += P @ V : A=P[m=cl][k], B-frag (ds,ks) = Vb[(ds*256+(j0>>3)+ks*4)*128+lane*8]
    #pragma unroll
    for (int ks = 0; ks < 4; ++ks) {
      const bf16x8 ap = *(const bf16x8*)&Pw[cl * 136 + ks * 32 + quad * 8];
      bf16x8 vf[4];
      #pragma unroll
      for (int ds = 0; ds < 4; ++ds)
        vf[ds] = *(const bf16x8*)&Vb[(size_t)((ds * 256 + (j0 >> 3) + ks * 4) * 128) + lane * 8];
      #pragma unroll
      for (int ds = 0; ds < 4; ++ds)
        o[ds] = __builtin_amdgcn_mfma_f32_16x16x32_bf16(ap, vf[ds], o[ds], 0, 0, 0);
    }
  }

  // final l reduction: row (quad*4+r) owned by 16 lanes sharing quad
  #pragma unroll
  for (int r = 0; r < 4; ++r) {
    #pragma unroll
    for (int msk = 1; msk < 16; msk <<= 1) lsum[r] += __shfl_xor(lsum[r], msk, 64);
  }

  const int b = bh >> 4, h = bh & 15;
  #pragma unroll
  for (int ds = 0; ds < 4; ++ds)
    #pragma unroll
    for (int r = 0; r < 4; ++r) {
      const int t = q0 + w * 16 + quad * 4 + r;
      const int d = ds * 16 + cl;
      Y[((size_t)b * 2048 + t) * 1024 + h * 64 + d] = f2bf(o[ds][r] / lsum[r]);
    }
}

extern "C" void kernel_launch(void* const* d_in, const int* in_sizes, int n_in,
                              void* d_out, int out_size, void* d_ws, size_t ws_size,
                              hipStream_t stream) {
  (void)in_sizes; (void)n_in; (void)out_size; (void)ws_size;
  const float* x  = (const float*)d_in[0];
  const float* Wq = (const float*)d_in[1];
  const float* Wk = (const float*)d_in[2];
  const float* Wv = (const float*)d_in[3];
  const float* Wo = (const float*)d_in[4];

  char* ws = (char*)d_ws;
  const size_t MB = 1024 * 1024;
  u16t* xb  = (u16t*)(ws);               // [4096][1024] bf16 (8 MB) — aliased by Yw
  u16t* Wqb = (u16t*)(ws + 8 * MB);      // Wq/Wk/Wv contiguous -> [3072][1024]
  u16t* Wkb = (u16t*)(ws + 10 * MB);
  u16t* Wvb = (u16t*)(ws + 12 * MB);
  u16t* Wob = (u16t*)(ws + 14 * MB);
  u16t* Qw  = (u16t*)(ws + 16 * MB);     // [32][2048][64] bf16 head-split (pre-scaled)
  u16t* Ktw = (u16t*)(ws + 24 * MB);     // [32] fragment-tiled K'
  u16t* Vtw = (u16t*)(ws + 32 * MB);     // [32] fragment-tiled V'
  u16t* Yw  = xb;                        // safe alias: xb dead after QKV gemm

  convert_bf16<<<8192, 256, 0, stream>>>(x, Wq, Wk, Wv, Wo, xb, Wqb, Wkb, Wvb, Wob);
  // fused QKV: B = [3072][1024], output target selected by n0>>10
  gemm_bt<1><<<dim3(24, 32), 256, 0, stream>>>(
      xb, Wqb, Qw, Ktw, Vtw, 4096, 3072, 1024);
  flash_attn<<<dim3(32, 32), 256, 0, stream>>>(Qw, Ktw, Vtw, Yw);
  gemm_bt<0><<<dim3(8, 32), 256, 0, stream>>>(
      Yw, Wob, d_out, d_out, d_out, 4096, 1024, 1024);
}